// Round 1
// baseline (3060.210 us; speedup 1.0000x reference)
//
#include <hip/hip_runtime.h>
#include <math.h>

#define D 128

// ---------- degree count ----------
__global__ void k_deg(const int* __restrict__ dst, int E, float* __restrict__ deg) {
    int i = blockIdx.x * blockDim.x + threadIdx.x;
    if (i < E) unsafeAtomicAdd(&deg[dst[i]], 1.0f);
}

// ---------- dinv = (deg+2)^-1/2 ----------
__global__ void k_dinv(const float* __restrict__ deg, float* __restrict__ dinv, int N) {
    int i = blockIdx.x * blockDim.x + threadIdx.x;
    if (i < N) dinv[i] = rsqrtf(deg[i] + 2.0f);
}

// ---------- xa = x * (2*dinv^2)  (self-loop term, also zero-inits xa) ----------
__global__ void k_xa_init(const float* __restrict__ x, const float* __restrict__ dinv,
                          float* __restrict__ xa, int N) {
    int i = blockIdx.x * blockDim.x + threadIdx.x;  // over N*32 float4s
    if (i >= N * (D / 4)) return;
    int n = i >> 5;
    float dd = dinv[n];
    float sfac = 2.0f * dd * dd;
    float4 v = ((const float4*)x)[i];
    v.x *= sfac; v.y *= sfac; v.z *= sfac; v.w *= sfac;
    ((float4*)xa)[i] = v;
}

// ---------- edge scatter: xa[dst] += x[src] * dinv[src]*dinv[dst] ----------
__global__ void k_scatter(const float* __restrict__ x, const int* __restrict__ src,
                          const int* __restrict__ dst, const float* __restrict__ dinv,
                          float* __restrict__ xa, int E) {
    long tid = (long)blockIdx.x * blockDim.x + threadIdx.x;  // over E*32 (float4 per thread)
    if (tid >= (long)E * 32) return;
    int e  = (int)(tid >> 5);
    int f4 = (int)(tid & 31);
    int s = src[e], d = dst[e];
    float norm = dinv[s] * dinv[d];
    float4 v = ((const float4*)(x + (size_t)s * D))[f4];
    float* o = xa + (size_t)d * D + f4 * 4;
    unsafeAtomicAdd(o + 0, v.x * norm);
    unsafeAtomicAdd(o + 1, v.y * norm);
    unsafeAtomicAdd(o + 2, v.z * norm);
    unsafeAtomicAdd(o + 3, v.w * norm);
}

// ---------- fold weights: M[k][j] (j<128: Wz@lzW_top, j>=128: Wh@lhW_top), c[256] ----------
__global__ void k_prep(const float* __restrict__ Wz, const float* __restrict__ bz,
                       const float* __restrict__ lzW, const float* __restrict__ lzb,
                       const float* __restrict__ Wh, const float* __restrict__ bh,
                       const float* __restrict__ lhW, const float* __restrict__ lhb,
                       float* __restrict__ M, float* __restrict__ c) {
    int j = threadIdx.x;   // 0..255
    int k = blockIdx.x;    // 0..127
    int jj = j & 127;
    const float* W = (j < 128) ? Wz : Wh;
    const float* L = (j < 128) ? lzW : lhW;   // only first 128 rows used (H0 part is zero)
    float s = 0.f;
    for (int t = 0; t < 128; ++t) s += W[k * 128 + t] * L[t * 128 + jj];
    M[k * 256 + j] = s;
    if (k == 0) {
        const float* b  = (j < 128) ? bz  : bh;
        const float* lb = (j < 128) ? lzb : lhb;
        float cs = lb[jj];
        for (int t = 0; t < 128; ++t) cs += b[t] * L[t * 128 + jj];
        c[j] = cs;
    }
}

// ---------- out init = b2 ----------
__global__ void k_out_init(float* __restrict__ out, const float* __restrict__ b2, int N) {
    int i = blockIdx.x * blockDim.x + threadIdx.x;
    if (i < N) out[i] = b2[0];
}

// ---------- fused epilogue: G = xa@M (+c), Z=sigmoid, Ht=tanh, out += sum (1-Z)*Ht*W2 ----------
__global__ __launch_bounds__(256) void k_epilogue(
    const float* __restrict__ xa, const float* __restrict__ M,
    const float* __restrict__ c, const float* __restrict__ W2,
    float* __restrict__ out, int N) {
    __shared__ float Ast[128][34];   // A transposed [k][n], padded
    __shared__ float Bs[128][64];    // cols 0..31: z-cols jc+..; 32..63: h-cols 128+jc+..
    __shared__ float Gs[32][65];     // pre-activations tile, padded

    int tid = threadIdx.x;
    int n0 = blockIdx.x * 32;
    int jc = blockIdx.y * 32;

    // load A tile (32 nodes x 128 k), transpose into LDS
    for (int i = 0; i < 4; ++i) {
        int q = tid + i * 256;           // 0..1023 float4s
        int n = q >> 5;
        int k4 = (q & 31) << 2;
        float4 v = make_float4(0.f, 0.f, 0.f, 0.f);
        if (n0 + n < N) v = *(const float4*)(xa + (size_t)(n0 + n) * D + k4);
        Ast[k4 + 0][n] = v.x; Ast[k4 + 1][n] = v.y;
        Ast[k4 + 2][n] = v.z; Ast[k4 + 3][n] = v.w;
    }
    // load B tile (128 k x 64 cols: 32 z + 32 h)
    for (int i = 0; i < 8; ++i) {
        int q = tid + i * 256;           // 0..2047 float4s
        int k = q >> 4;
        int j4 = (q & 15) << 2;
        int col = (j4 < 32) ? (jc + j4) : (96 + jc + j4);  // 128 + jc + (j4-32)
        *(float4*)&Bs[k][j4] = *(const float4*)(M + k * 256 + col);
    }
    __syncthreads();

    int tx = tid & 15, ty = tid >> 4;    // micro-tile: 2 nodes x 4 cols
    float acc[2][4] = {{0.f,0.f,0.f,0.f},{0.f,0.f,0.f,0.f}};
    for (int k = 0; k < 128; ++k) {
        float2 a = *(const float2*)&Ast[k][2 * ty];
        float4 b = *(const float4*)&Bs[k][4 * tx];
        acc[0][0] += a.x * b.x; acc[0][1] += a.x * b.y;
        acc[0][2] += a.x * b.z; acc[0][3] += a.x * b.w;
        acc[1][0] += a.y * b.x; acc[1][1] += a.y * b.y;
        acc[1][2] += a.y * b.z; acc[1][3] += a.y * b.w;
    }
    for (int i = 0; i < 2; ++i)
        for (int jj = 0; jj < 4; ++jj)
            Gs[2 * ty + i][4 * tx + jj] = acc[i][jj];
    __syncthreads();

    // reduce: 32 nodes x 8 lanes, each lane handles 4 col-pairs
    int n = tid >> 3, l = tid & 7;
    float p = 0.f;
    for (int jj = 0; jj < 4; ++jj) {
        int j = l * 4 + jj;
        float gz = Gs[n][j]      + c[jc + j];
        float gh = Gs[n][32 + j] + c[128 + jc + j];
        float z  = 1.f / (1.f + __expf(-gz));
        float ht = tanhf(gh);
        p += (1.f - z) * ht * W2[jc + j];
    }
    p += __shfl_xor(p, 1);
    p += __shfl_xor(p, 2);
    p += __shfl_xor(p, 4);
    if (l == 0 && n0 + n < N) unsafeAtomicAdd(&out[n0 + n], p);
}

extern "C" void kernel_launch(void* const* d_in, const int* in_sizes, int n_in,
                              void* d_out, int out_size, void* d_ws, size_t ws_size,
                              hipStream_t stream) {
    const float* x    = (const float*)d_in[0];
    const int*   eidx = (const int*)d_in[1];
    const float* Wz   = (const float*)d_in[2];
    const float* bz   = (const float*)d_in[3];
    const float* Wh   = (const float*)d_in[6];
    const float* bh   = (const float*)d_in[7];
    const float* lzW  = (const float*)d_in[8];
    const float* lzb  = (const float*)d_in[9];
    const float* lhW  = (const float*)d_in[12];
    const float* lhb  = (const float*)d_in[13];
    const float* W2   = (const float*)d_in[14];
    const float* b2   = (const float*)d_in[15];
    float* out = (float*)d_out;

    int N = in_sizes[0] / D;          // 100000
    int E = in_sizes[1] / 2;          // 1600000
    const int* src = eidx;
    const int* dst = eidx + E;

    // workspace layout (bytes)
    char* ws = (char*)d_ws;
    float* xa   = (float*)(ws);                               // N*128 floats
    float* deg  = (float*)(ws + (size_t)N * D * 4);           // N floats
    float* dinv = (float*)(ws + (size_t)N * D * 4 + (size_t)N * 4);
    float* M    = (float*)(ws + (size_t)N * D * 4 + (size_t)N * 8);
    float* c    = (float*)(ws + (size_t)N * D * 4 + (size_t)N * 8 + 128 * 256 * 4);

    hipMemsetAsync(deg, 0, (size_t)N * sizeof(float), stream);

    k_deg<<<(E + 255) / 256, 256, 0, stream>>>(dst, E, deg);
    k_dinv<<<(N + 255) / 256, 256, 0, stream>>>(deg, dinv, N);
    k_xa_init<<<(N * (D / 4) + 255) / 256, 256, 0, stream>>>(x, dinv, xa, N);
    k_scatter<<<(int)(((long)E * 32 + 255) / 256), 256, 0, stream>>>(x, src, dst, dinv, xa, E);
    k_prep<<<128, 256, 0, stream>>>(Wz, bz, lzW, lzb, Wh, bh, lhW, lhb, M, c);
    k_out_init<<<(N + 255) / 256, 256, 0, stream>>>(out, b2, N);
    dim3 eg((N + 31) / 32, 4);
    k_epilogue<<<eg, 256, 0, stream>>>(xa, M, c, W2, out, N);
}

// Round 2
// 561.389 us; speedup vs baseline: 5.4511x; 5.4511x over previous
//
#include <hip/hip_runtime.h>
#include <math.h>

#define D 128
#define SCAN_B 1024

// ---------- per-dst edge count ----------
__global__ void k_count(const int* __restrict__ dst, int E, int* __restrict__ counts) {
    int i = blockIdx.x * blockDim.x + threadIdx.x;
    if (i < E) atomicAdd(&counts[dst[i]], 1);
}

// ---------- scan pass A: per-1024-chunk sums ----------
__global__ void k_bsum(const int* __restrict__ counts, int N, int* __restrict__ bsum) {
    __shared__ int sd[256];
    int b = blockIdx.x, t = threadIdx.x;
    int base = b * SCAN_B + t * 4;
    int s = 0;
    for (int i = 0; i < 4; ++i) { int idx = base + i; if (idx < N) s += counts[idx]; }
    sd[t] = s; __syncthreads();
    for (int off = 128; off > 0; off >>= 1) { if (t < off) sd[t] += sd[t + off]; __syncthreads(); }
    if (t == 0) bsum[b] = sd[0];
}

// ---------- scan pass B: exclusive scan of chunk sums (B~98, single thread) ----------
__global__ void k_scan_bsum(int* __restrict__ bsum, int B, int* __restrict__ rowptr, int N) {
    if (blockIdx.x == 0 && threadIdx.x == 0) {
        int acc = 0;
        for (int i = 0; i < B; ++i) { int v = bsum[i]; bsum[i] = acc; acc += v; }
        rowptr[N] = acc;
    }
}

// ---------- scan pass C: fill rowptr ----------
__global__ void k_scan_fill(const int* __restrict__ counts, int N,
                            const int* __restrict__ bsum, int* __restrict__ rowptr) {
    __shared__ int ts[256];
    int b = blockIdx.x, t = threadIdx.x;
    int base = b * SCAN_B + t * 4;
    int v[4]; int s = 0;
    for (int i = 0; i < 4; ++i) { int idx = base + i; v[i] = (idx < N) ? counts[idx] : 0; s += v[i]; }
    ts[t] = s; __syncthreads();
    for (int off = 1; off < 256; off <<= 1) {
        int add = (t >= off) ? ts[t - off] : 0;
        __syncthreads();
        ts[t] += add;
        __syncthreads();
    }
    int run = bsum[b] + ts[t] - s;   // exclusive prefix
    for (int i = 0; i < 4; ++i) {
        int idx = base + i;
        if (idx < N) rowptr[idx] = run;
        run += v[i];
    }
}

// ---------- dinv = (count+2)^-1/2 ----------
__global__ void k_dinv(const int* __restrict__ counts, float* __restrict__ dinv, int N) {
    int i = blockIdx.x * blockDim.x + threadIdx.x;
    if (i < N) dinv[i] = rsqrtf((float)counts[i] + 2.0f);
}

// ---------- place edges into CSR (destroys counts) ----------
__global__ void k_place(const int* __restrict__ src, const int* __restrict__ dst, int E,
                        const int* __restrict__ rowptr, int* __restrict__ counts,
                        int* __restrict__ esrc) {
    int e = blockIdx.x * blockDim.x + threadIdx.x;
    if (e >= E) return;
    int d = dst[e];
    int old = atomicSub(&counts[d], 1);
    esrc[rowptr[d] + old - 1] = src[e];
}

// ---------- gather: one wave per node, xa[d] = dinv[d]*sum dinv[s]*x[s] + 2*dinv[d]^2*x[d] ----------
__global__ __launch_bounds__(256) void k_gather(const float* __restrict__ x,
                                                const int* __restrict__ esrc,
                                                const int* __restrict__ rowptr,
                                                const float* __restrict__ dinv,
                                                float* __restrict__ xa, int N) {
    int gw = (blockIdx.x * blockDim.x + threadIdx.x) >> 6;
    int lane = threadIdx.x & 63;
    if (gw >= N) return;
    int d = gw;
    int start = rowptr[d], end = rowptr[d + 1];
    float dd = dinv[d];
    float2 acc0 = make_float2(0.f, 0.f), acc1 = make_float2(0.f, 0.f);
    const float* xb = x + lane * 2;
    for (int base = start; base < end; base += 64) {
        int cnt = min(64, end - base);
        int myedge = 0; float mynorm = 0.f;
        if (lane < cnt) { myedge = esrc[base + lane]; mynorm = dinv[myedge]; }
        int i = 0;
        for (; i + 1 < cnt; i += 2) {
            int   s0 = __shfl(myedge, i);     float n0 = __shfl(mynorm, i);
            int   s1 = __shfl(myedge, i + 1); float n1 = __shfl(mynorm, i + 1);
            float2 v0 = *(const float2*)(xb + (size_t)s0 * D);
            float2 v1 = *(const float2*)(xb + (size_t)s1 * D);
            acc0.x += v0.x * n0; acc0.y += v0.y * n0;
            acc1.x += v1.x * n1; acc1.y += v1.y * n1;
        }
        if (i < cnt) {
            int s0 = __shfl(myedge, i); float n0 = __shfl(mynorm, i);
            float2 v0 = *(const float2*)(xb + (size_t)s0 * D);
            acc0.x += v0.x * n0; acc0.y += v0.y * n0;
        }
    }
    float2 xs = *(const float2*)(x + (size_t)d * D + lane * 2);
    float sfac = 2.f * dd * dd;
    float2 r;
    r.x = (acc0.x + acc1.x) * dd + xs.x * sfac;
    r.y = (acc0.y + acc1.y) * dd + xs.y * sfac;
    *(float2*)(xa + (size_t)d * D + lane * 2) = r;
}

// ---------- fold weights: M[k][j] (j<128: Wz@lzW_top, j>=128: Wh@lhW_top), c[256] ----------
__global__ void k_prep(const float* __restrict__ Wz, const float* __restrict__ bz,
                       const float* __restrict__ lzW, const float* __restrict__ lzb,
                       const float* __restrict__ Wh, const float* __restrict__ bh,
                       const float* __restrict__ lhW, const float* __restrict__ lhb,
                       float* __restrict__ M, float* __restrict__ c) {
    int j = threadIdx.x;   // 0..255
    int k = blockIdx.x;    // 0..127
    int jj = j & 127;
    const float* W = (j < 128) ? Wz : Wh;
    const float* L = (j < 128) ? lzW : lhW;   // only first 128 rows used (H0 part is zero)
    float s = 0.f;
    for (int t = 0; t < 128; ++t) s += W[k * 128 + t] * L[t * 128 + jj];
    M[k * 256 + j] = s;
    if (k == 0) {
        const float* b  = (j < 128) ? bz  : bh;
        const float* lb = (j < 128) ? lzb : lhb;
        float cs = lb[jj];
        for (int t = 0; t < 128; ++t) cs += b[t] * L[t * 128 + jj];
        c[j] = cs;
    }
}

// ---------- out init = b2 ----------
__global__ void k_out_init(float* __restrict__ out, const float* __restrict__ b2, int N) {
    int i = blockIdx.x * blockDim.x + threadIdx.x;
    if (i < N) out[i] = b2[0];
}

// ---------- fused epilogue: G = xa@M (+c), Z=sigmoid, Ht=tanh, out += sum (1-Z)*Ht*W2 ----------
__global__ __launch_bounds__(256) void k_epilogue(
    const float* __restrict__ xa, const float* __restrict__ M,
    const float* __restrict__ c, const float* __restrict__ W2,
    float* __restrict__ out, int N) {
    __shared__ float Ast[128][34];   // A transposed [k][n], padded
    __shared__ float Bs[128][64];    // cols 0..31: z-cols jc+..; 32..63: h-cols 128+jc+..
    __shared__ float Gs[32][65];     // pre-activations tile, padded

    int tid = threadIdx.x;
    int n0 = blockIdx.x * 32;
    int jc = blockIdx.y * 32;

    // load A tile (32 nodes x 128 k), transpose into LDS
    for (int i = 0; i < 4; ++i) {
        int q = tid + i * 256;           // 0..1023 float4s
        int n = q >> 5;
        int k4 = (q & 31) << 2;
        float4 v = make_float4(0.f, 0.f, 0.f, 0.f);
        if (n0 + n < N) v = *(const float4*)(xa + (size_t)(n0 + n) * D + k4);
        Ast[k4 + 0][n] = v.x; Ast[k4 + 1][n] = v.y;
        Ast[k4 + 2][n] = v.z; Ast[k4 + 3][n] = v.w;
    }
    // load B tile (128 k x 64 cols: 32 z + 32 h)
    for (int i = 0; i < 8; ++i) {
        int q = tid + i * 256;           // 0..2047 float4s
        int k = q >> 4;
        int j4 = (q & 15) << 2;
        int col = (j4 < 32) ? (jc + j4) : (96 + jc + j4);  // 128 + jc + (j4-32)
        *(float4*)&Bs[k][j4] = *(const float4*)(M + k * 256 + col);
    }
    __syncthreads();

    int tx = tid & 15, ty = tid >> 4;    // micro-tile: 2 nodes x 4 cols
    float acc[2][4] = {{0.f,0.f,0.f,0.f},{0.f,0.f,0.f,0.f}};
    for (int k = 0; k < 128; ++k) {
        float2 a = *(const float2*)&Ast[k][2 * ty];
        float4 b = *(const float4*)&Bs[k][4 * tx];
        acc[0][0] += a.x * b.x; acc[0][1] += a.x * b.y;
        acc[0][2] += a.x * b.z; acc[0][3] += a.x * b.w;
        acc[1][0] += a.y * b.x; acc[1][1] += a.y * b.y;
        acc[1][2] += a.y * b.z; acc[1][3] += a.y * b.w;
    }
    for (int i = 0; i < 2; ++i)
        for (int jj = 0; jj < 4; ++jj)
            Gs[2 * ty + i][4 * tx + jj] = acc[i][jj];
    __syncthreads();

    // reduce: 32 nodes x 8 lanes, each lane handles 4 col-pairs
    int n = tid >> 3, l = tid & 7;
    float p = 0.f;
    for (int jj = 0; jj < 4; ++jj) {
        int j = l * 4 + jj;
        float gz = Gs[n][j]      + c[jc + j];
        float gh = Gs[n][32 + j] + c[128 + jc + j];
        float z  = 1.f / (1.f + __expf(-gz));
        float ht = tanhf(gh);
        p += (1.f - z) * ht * W2[jc + j];
    }
    p += __shfl_xor(p, 1);
    p += __shfl_xor(p, 2);
    p += __shfl_xor(p, 4);
    if (l == 0 && n0 + n < N) unsafeAtomicAdd(&out[n0 + n], p);
}

extern "C" void kernel_launch(void* const* d_in, const int* in_sizes, int n_in,
                              void* d_out, int out_size, void* d_ws, size_t ws_size,
                              hipStream_t stream) {
    const float* x    = (const float*)d_in[0];
    const int*   eidx = (const int*)d_in[1];
    const float* Wz   = (const float*)d_in[2];
    const float* bz   = (const float*)d_in[3];
    const float* Wh   = (const float*)d_in[6];
    const float* bh   = (const float*)d_in[7];
    const float* lzW  = (const float*)d_in[8];
    const float* lzb  = (const float*)d_in[9];
    const float* lhW  = (const float*)d_in[12];
    const float* lhb  = (const float*)d_in[13];
    const float* W2   = (const float*)d_in[14];
    const float* b2   = (const float*)d_in[15];
    float* out = (float*)d_out;

    int N = in_sizes[0] / D;          // 100000
    int E = in_sizes[1] / 2;          // 1600000
    const int* src = eidx;
    const int* dst = eidx + E;
    int B = (N + SCAN_B - 1) / SCAN_B;

    // workspace layout (bytes)
    char* ws = (char*)d_ws;
    size_t off = 0;
    float* xa     = (float*)(ws + off); off += (size_t)N * D * 4;
    int*   counts = (int*)  (ws + off); off += (size_t)N * 4;
    int*   rowptr = (int*)  (ws + off); off += (size_t)(N + 1) * 4;
    float* dinv   = (float*)(ws + off); off += (size_t)N * 4;
    int*   esrc   = (int*)  (ws + off); off += (size_t)E * 4;
    int*   bsum   = (int*)  (ws + off); off += (size_t)B * 4 + 64;
    float* M      = (float*)(ws + off); off += 128 * 256 * 4;
    float* c      = (float*)(ws + off); off += 256 * 4;

    hipMemsetAsync(counts, 0, (size_t)N * sizeof(int), stream);

    k_count<<<(E + 255) / 256, 256, 0, stream>>>(dst, E, counts);
    k_bsum<<<B, 256, 0, stream>>>(counts, N, bsum);
    k_scan_bsum<<<1, 64, 0, stream>>>(bsum, B, rowptr, N);
    k_scan_fill<<<B, 256, 0, stream>>>(counts, N, bsum, rowptr);
    k_dinv<<<(N + 255) / 256, 256, 0, stream>>>(counts, dinv, N);
    k_place<<<(E + 255) / 256, 256, 0, stream>>>(src, dst, E, rowptr, counts, esrc);
    k_gather<<<(N * 64 + 255) / 256, 256, 0, stream>>>(x, esrc, rowptr, dinv, xa, N);
    k_prep<<<128, 256, 0, stream>>>(Wz, bz, lzW, lzb, Wh, bh, lhW, lhb, M, c);
    k_out_init<<<(N + 255) / 256, 256, 0, stream>>>(out, b2, N);
    dim3 eg((N + 31) / 32, 4);
    k_epilogue<<<eg, 256, 0, stream>>>(xa, M, c, W2, out, N);
}

// Round 3
// 525.534 us; speedup vs baseline: 5.8230x; 1.0682x over previous
//
#include <hip/hip_runtime.h>
#include <math.h>

#define D 128
#define SCAN_B 1024

// ---------- per-dst edge count ----------
__global__ void k_count(const int* __restrict__ dst, int E, int* __restrict__ counts) {
    int i = blockIdx.x * blockDim.x + threadIdx.x;
    if (i < E) atomicAdd(&counts[dst[i]], 1);
}

// ---------- scan pass A: per-1024-chunk sums ----------
__global__ void k_bsum(const int* __restrict__ counts, int N, int* __restrict__ bsum) {
    __shared__ int sd[256];
    int b = blockIdx.x, t = threadIdx.x;
    int base = b * SCAN_B + t * 4;
    int s = 0;
    for (int i = 0; i < 4; ++i) { int idx = base + i; if (idx < N) s += counts[idx]; }
    sd[t] = s; __syncthreads();
    for (int off = 128; off > 0; off >>= 1) { if (t < off) sd[t] += sd[t + off]; __syncthreads(); }
    if (t == 0) bsum[b] = sd[0];
}

// ---------- scan pass B: exclusive scan of chunk sums ----------
__global__ void k_scan_bsum(int* __restrict__ bsum, int B, int* __restrict__ rowptr, int N) {
    if (blockIdx.x == 0 && threadIdx.x == 0) {
        int acc = 0;
        for (int i = 0; i < B; ++i) { int v = bsum[i]; bsum[i] = acc; acc += v; }
        rowptr[N] = acc;
    }
}

// ---------- scan pass C: fill rowptr ----------
__global__ void k_scan_fill(const int* __restrict__ counts, int N,
                            const int* __restrict__ bsum, int* __restrict__ rowptr) {
    __shared__ int ts[256];
    int b = blockIdx.x, t = threadIdx.x;
    int base = b * SCAN_B + t * 4;
    int v[4]; int s = 0;
    for (int i = 0; i < 4; ++i) { int idx = base + i; v[i] = (idx < N) ? counts[idx] : 0; s += v[i]; }
    ts[t] = s; __syncthreads();
    for (int off = 1; off < 256; off <<= 1) {
        int add = (t >= off) ? ts[t - off] : 0;
        __syncthreads();
        ts[t] += add;
        __syncthreads();
    }
    int run = bsum[b] + ts[t] - s;   // exclusive prefix
    for (int i = 0; i < 4; ++i) {
        int idx = base + i;
        if (idx < N) rowptr[idx] = run;
        run += v[i];
    }
}

// ---------- dinv = (count+2)^-1/2 ----------
__global__ void k_dinv(const int* __restrict__ counts, float* __restrict__ dinv, int N) {
    int i = blockIdx.x * blockDim.x + threadIdx.x;
    if (i < N) dinv[i] = rsqrtf((float)counts[i] + 2.0f);
}

// ---------- place edges into CSR (destroys counts) ----------
__global__ void k_place(const int* __restrict__ src, const int* __restrict__ dst, int E,
                        const int* __restrict__ rowptr, int* __restrict__ counts,
                        int* __restrict__ esrc) {
    int e = blockIdx.x * blockDim.x + threadIdx.x;
    if (e >= E) return;
    int d = dst[e];
    int old = atomicSub(&counts[d], 1);
    esrc[rowptr[d] + old - 1] = src[e];
}

// ---------- gather v2: half-wave (32 lanes) per node, float4/lane ----------
__global__ __launch_bounds__(256) void k_gather(const float* __restrict__ x,
                                                const int* __restrict__ esrc,
                                                const int* __restrict__ rowptr,
                                                const float* __restrict__ dinv,
                                                float* __restrict__ xa, int N) {
    int node = (blockIdx.x * blockDim.x + threadIdx.x) >> 5;
    int sub  = threadIdx.x & 31;
    if (node >= N) return;
    int start = rowptr[node], end = rowptr[node + 1];
    float dd = dinv[node];
    float4 acc0 = make_float4(0.f, 0.f, 0.f, 0.f);
    float4 acc1 = make_float4(0.f, 0.f, 0.f, 0.f);
    for (int base = start; base < end; base += 32) {
        int cnt = min(32, end - base);
        int myedge = 0; float mynorm = 0.f;
        if (sub < cnt) { myedge = esrc[base + sub]; mynorm = dinv[myedge]; }
        int i = 0;
        for (; i + 1 < cnt; i += 2) {
            int   s0 = __shfl(myedge, i,     32); float n0 = __shfl(mynorm, i,     32);
            int   s1 = __shfl(myedge, i + 1, 32); float n1 = __shfl(mynorm, i + 1, 32);
            float4 v0 = ((const float4*)(x + (size_t)s0 * D))[sub];
            float4 v1 = ((const float4*)(x + (size_t)s1 * D))[sub];
            acc0.x += v0.x * n0; acc0.y += v0.y * n0; acc0.z += v0.z * n0; acc0.w += v0.w * n0;
            acc1.x += v1.x * n1; acc1.y += v1.y * n1; acc1.z += v1.z * n1; acc1.w += v1.w * n1;
        }
        if (i < cnt) {
            int s0 = __shfl(myedge, i, 32); float n0 = __shfl(mynorm, i, 32);
            float4 v0 = ((const float4*)(x + (size_t)s0 * D))[sub];
            acc0.x += v0.x * n0; acc0.y += v0.y * n0; acc0.z += v0.z * n0; acc0.w += v0.w * n0;
        }
    }
    float4 xs = ((const float4*)(x + (size_t)node * D))[sub];
    float sfac = 2.f * dd * dd;
    float4 r;
    r.x = (acc0.x + acc1.x) * dd + xs.x * sfac;
    r.y = (acc0.y + acc1.y) * dd + xs.y * sfac;
    r.z = (acc0.z + acc1.z) * dd + xs.z * sfac;
    r.w = (acc0.w + acc1.w) * dd + xs.w * sfac;
    ((float4*)(xa + (size_t)node * D))[sub] = r;
}

// ---------- fold weights: M[k][j] (j<128: Wz@lzW_top, j>=128: Wh@lhW_top), c[256] ----------
__global__ void k_prep(const float* __restrict__ Wz, const float* __restrict__ bz,
                       const float* __restrict__ lzW, const float* __restrict__ lzb,
                       const float* __restrict__ Wh, const float* __restrict__ bh,
                       const float* __restrict__ lhW, const float* __restrict__ lhb,
                       float* __restrict__ M, float* __restrict__ c) {
    int j = threadIdx.x;   // 0..255
    int k = blockIdx.x;    // 0..127
    int jj = j & 127;
    const float* W = (j < 128) ? Wz : Wh;
    const float* L = (j < 128) ? lzW : lhW;   // only first 128 rows used (H0 part is zero)
    float s = 0.f;
    for (int t = 0; t < 128; ++t) s += W[k * 128 + t] * L[t * 128 + jj];
    M[k * 256 + j] = s;
    if (k == 0) {
        const float* b  = (j < 128) ? bz  : bh;
        const float* lb = (j < 128) ? lzb : lhb;
        float cs = lb[jj];
        for (int t = 0; t < 128; ++t) cs += b[t] * L[t * 128 + jj];
        c[j] = cs;
    }
}

// ---------- out init = b2 ----------
__global__ void k_out_init(float* __restrict__ out, const float* __restrict__ b2, int N) {
    int i = blockIdx.x * blockDim.x + threadIdx.x;
    if (i < N) out[i] = b2[0];
}

// ---------- epilogue v3: 128x128 tile, 8x8 micro-tile, conflict-free LDS ----------
// Block handles nodes [n0, n0+128) and col-pair group gy: z-cols 64*gy..64*gy+63,
// h-cols 128+64*gy..128+64*gy+63. acc[u][0..3]=z, acc[u][4..7]=h.
#define KC 32
#define ASTRIDE 130
__global__ __launch_bounds__(256, 4) void k_epilogue(
    const float* __restrict__ xa, const float* __restrict__ M,
    const float* __restrict__ c, const float* __restrict__ W2,
    float* __restrict__ out, int N) {
    __shared__ float Ast[KC * ASTRIDE];   // [k][n], stride 130 (8B-aligned rows, conflict-free b64 reads)
    __shared__ float Bs[KC * 128];        // [k][t]: t<64 z-cols, t>=64 h-cols

    int tid = threadIdx.x;
    int n0 = blockIdx.x * 128;
    int gy = blockIdx.y;                  // 0..1
    int tr = tid & 15, tc = tid >> 4;

    float acc[8][8];
    #pragma unroll
    for (int u = 0; u < 8; ++u)
        #pragma unroll
        for (int v = 0; v < 8; ++v) acc[u][v] = 0.f;

    for (int kc = 0; kc < 128; kc += KC) {
        // load A chunk: 128 nodes x 32 k
        #pragma unroll
        for (int i = 0; i < 4; ++i) {
            int idx = tid + 256 * i;          // 0..1023
            int n = idx >> 3;
            int k4 = (idx & 7) * 4;
            float4 v = make_float4(0.f, 0.f, 0.f, 0.f);
            if (n0 + n < N) v = *(const float4*)(xa + (size_t)(n0 + n) * D + kc + k4);
            Ast[(k4 + 0) * ASTRIDE + n] = v.x;
            Ast[(k4 + 1) * ASTRIDE + n] = v.y;
            Ast[(k4 + 2) * ASTRIDE + n] = v.z;
            Ast[(k4 + 3) * ASTRIDE + n] = v.w;
        }
        // load B chunk: 32 k x 128 cols (64 z + 64 h)
        #pragma unroll
        for (int i = 0; i < 4; ++i) {
            int idx = tid + 256 * i;          // 0..1023
            int k = idx >> 5;
            int t0 = (idx & 31) * 4;
            int col = (t0 < 64) ? (64 * gy + t0) : (64 + 64 * gy + t0);
            *(float4*)&Bs[k * 128 + t0] = *(const float4*)(M + (size_t)(kc + k) * 256 + col);
        }
        __syncthreads();

        #pragma unroll 8
        for (int k = 0; k < KC; ++k) {
            float a[8], b[8];
            #pragma unroll
            for (int q = 0; q < 4; ++q) {
                float2 t = *(const float2*)&Ast[k * ASTRIDE + 2 * tr + 32 * q];
                a[2 * q] = t.x; a[2 * q + 1] = t.y;
            }
            float4 bz = *(const float4*)&Bs[k * 128 + 4 * tc];
            float4 bh = *(const float4*)&Bs[k * 128 + 64 + 4 * tc];
            b[0] = bz.x; b[1] = bz.y; b[2] = bz.z; b[3] = bz.w;
            b[4] = bh.x; b[5] = bh.y; b[6] = bh.z; b[7] = bh.w;
            #pragma unroll
            for (int u = 0; u < 8; ++u)
                #pragma unroll
                for (int v = 0; v < 8; ++v)
                    acc[u][v] += a[u] * b[v];
        }
        __syncthreads();
    }

    // fused activation + W2 dot
    float p[8];
    #pragma unroll
    for (int u = 0; u < 8; ++u) {
        float s = 0.f;
        #pragma unroll
        for (int v = 0; v < 4; ++v) {
            int jz = 64 * gy + 4 * tc + v;
            float gz = acc[u][v]     + c[jz];
            float gh = acc[u][4 + v] + c[128 + jz];
            float z  = 1.f / (1.f + __expf(-gz));
            float ht = tanhf(gh);
            s += (1.f - z) * ht * W2[jz];
        }
        p[u] = s;
    }
    // reduce over tc within wave (lane bits 4,5), then 1 atomic per node per wave
    #pragma unroll
    for (int u = 0; u < 8; ++u) {
        p[u] += __shfl_xor(p[u], 16);
        p[u] += __shfl_xor(p[u], 32);
    }
    if ((tid & 48) == 0) {
        #pragma unroll
        for (int u = 0; u < 8; ++u) {
            int n = 2 * tr + 32 * (u >> 1) + (u & 1);
            if (n0 + n < N) unsafeAtomicAdd(&out[n0 + n], p[u]);
        }
    }
}

extern "C" void kernel_launch(void* const* d_in, const int* in_sizes, int n_in,
                              void* d_out, int out_size, void* d_ws, size_t ws_size,
                              hipStream_t stream) {
    const float* x    = (const float*)d_in[0];
    const int*   eidx = (const int*)d_in[1];
    const float* Wz   = (const float*)d_in[2];
    const float* bz   = (const float*)d_in[3];
    const float* Wh   = (const float*)d_in[6];
    const float* bh   = (const float*)d_in[7];
    const float* lzW  = (const float*)d_in[8];
    const float* lzb  = (const float*)d_in[9];
    const float* lhW  = (const float*)d_in[12];
    const float* lhb  = (const float*)d_in[13];
    const float* W2   = (const float*)d_in[14];
    const float* b2   = (const float*)d_in[15];
    float* out = (float*)d_out;

    int N = in_sizes[0] / D;          // 100000
    int E = in_sizes[1] / 2;          // 1600000
    const int* src = eidx;
    const int* dst = eidx + E;
    int B = (N + SCAN_B - 1) / SCAN_B;

    // workspace layout (bytes)
    char* ws = (char*)d_ws;
    size_t off = 0;
    float* xa     = (float*)(ws + off); off += (size_t)N * D * 4;
    int*   counts = (int*)  (ws + off); off += (size_t)N * 4;
    int*   rowptr = (int*)  (ws + off); off += (size_t)(N + 1) * 4;
    float* dinv   = (float*)(ws + off); off += (size_t)N * 4;
    int*   esrc   = (int*)  (ws + off); off += (size_t)E * 4;
    int*   bsum   = (int*)  (ws + off); off += (size_t)B * 4 + 64;
    float* M      = (float*)(ws + off); off += 128 * 256 * 4;
    float* c      = (float*)(ws + off); off += 256 * 4;

    hipMemsetAsync(counts, 0, (size_t)N * sizeof(int), stream);

    k_count<<<(E + 255) / 256, 256, 0, stream>>>(dst, E, counts);
    k_bsum<<<B, 256, 0, stream>>>(counts, N, bsum);
    k_scan_bsum<<<1, 64, 0, stream>>>(bsum, B, rowptr, N);
    k_scan_fill<<<B, 256, 0, stream>>>(counts, N, bsum, rowptr);
    k_dinv<<<(N + 255) / 256, 256, 0, stream>>>(counts, dinv, N);
    k_place<<<(E + 255) / 256, 256, 0, stream>>>(src, dst, E, rowptr, counts, esrc);
    k_gather<<<(N * 32 + 255) / 256, 256, 0, stream>>>(x, esrc, rowptr, dinv, xa, N);
    k_prep<<<128, 256, 0, stream>>>(Wz, bz, lzW, lzb, Wh, bh, lhW, lhb, M, c);
    k_out_init<<<(N + 255) / 256, 256, 0, stream>>>(out, b2, N);
    dim3 eg((N + 127) / 128, 2);
    k_epilogue<<<eg, 256, 0, stream>>>(xa, M, c, W2, out, N);
}

// Round 4
// 450.160 us; speedup vs baseline: 6.7981x; 1.1674x over previous
//
#include <hip/hip_runtime.h>
#include <math.h>

#define D 128
#define SCAN_B 1024

typedef __attribute__((ext_vector_type(8))) short s8v;
typedef __attribute__((ext_vector_type(8))) unsigned short us8;
typedef __attribute__((ext_vector_type(4))) unsigned short us4;
typedef __attribute__((ext_vector_type(4))) float f4v;

__device__ __forceinline__ float bf2f(unsigned short u) {
    union { unsigned int i; float f; } v; v.i = ((unsigned int)u) << 16; return v.f;
}
__device__ __forceinline__ unsigned short f2bf(float f) {
    union { float f; unsigned int i; } v; v.f = f;
    unsigned int r = v.i + 0x7FFFu + ((v.i >> 16) & 1u);
    return (unsigned short)(r >> 16);
}

// ---------- per-dst edge count ----------
__global__ void k_count(const int* __restrict__ dst, int E, int* __restrict__ counts) {
    int i = blockIdx.x * blockDim.x + threadIdx.x;
    if (i < E) atomicAdd(&counts[dst[i]], 1);
}

// ---------- scan pass A: per-1024-chunk sums ----------
__global__ void k_bsum(const int* __restrict__ counts, int N, int* __restrict__ bsum) {
    __shared__ int sd[256];
    int b = blockIdx.x, t = threadIdx.x;
    int base = b * SCAN_B + t * 4;
    int s = 0;
    for (int i = 0; i < 4; ++i) { int idx = base + i; if (idx < N) s += counts[idx]; }
    sd[t] = s; __syncthreads();
    for (int off = 128; off > 0; off >>= 1) { if (t < off) sd[t] += sd[t + off]; __syncthreads(); }
    if (t == 0) bsum[b] = sd[0];
}

// ---------- scan pass B: exclusive scan of chunk sums ----------
__global__ void k_scan_bsum(int* __restrict__ bsum, int B, int* __restrict__ rowptr, int N) {
    if (blockIdx.x == 0 && threadIdx.x == 0) {
        int acc = 0;
        for (int i = 0; i < B; ++i) { int v = bsum[i]; bsum[i] = acc; acc += v; }
        rowptr[N] = acc;
    }
}

// ---------- scan pass C: fill rowptr ----------
__global__ void k_scan_fill(const int* __restrict__ counts, int N,
                            const int* __restrict__ bsum, int* __restrict__ rowptr) {
    __shared__ int ts[256];
    int b = blockIdx.x, t = threadIdx.x;
    int base = b * SCAN_B + t * 4;
    int v[4]; int s = 0;
    for (int i = 0; i < 4; ++i) { int idx = base + i; v[i] = (idx < N) ? counts[idx] : 0; s += v[i]; }
    ts[t] = s; __syncthreads();
    for (int off = 1; off < 256; off <<= 1) {
        int add = (t >= off) ? ts[t - off] : 0;
        __syncthreads();
        ts[t] += add;
        __syncthreads();
    }
    int run = bsum[b] + ts[t] - s;   // exclusive prefix
    for (int i = 0; i < 4; ++i) {
        int idx = base + i;
        if (idx < N) rowptr[idx] = run;
        run += v[i];
    }
}

// ---------- dinv = (count+2)^-1/2 ----------
__global__ void k_dinv(const int* __restrict__ counts, float* __restrict__ dinv, int N) {
    int i = blockIdx.x * blockDim.x + threadIdx.x;
    if (i < N) dinv[i] = rsqrtf((float)counts[i] + 2.0f);
}

// ---------- place edges into CSR (destroys counts) ----------
__global__ void k_place(const int* __restrict__ src, const int* __restrict__ dst, int E,
                        const int* __restrict__ rowptr, int* __restrict__ counts,
                        int* __restrict__ esrc) {
    int e = blockIdx.x * blockDim.x + threadIdx.x;
    if (e >= E) return;
    int d = dst[e];
    int old = atomicSub(&counts[d], 1);
    esrc[rowptr[d] + old - 1] = src[e];
}

// ---------- cast x to bf16 ----------
__global__ void k_xcast(const float* __restrict__ x, unsigned short* __restrict__ xb, int n4) {
    int i = blockIdx.x * blockDim.x + threadIdx.x;
    if (i >= n4) return;
    float4 v = ((const float4*)x)[i];
    us4 o;
    o[0] = f2bf(v.x); o[1] = f2bf(v.y); o[2] = f2bf(v.z); o[3] = f2bf(v.w);
    ((us4*)xb)[i] = o;
}

// ---------- gather v3: half-wave per node, 2 edges/step, bf16 rows ----------
__global__ __launch_bounds__(256) void k_gather(const unsigned short* __restrict__ xb,
                                                const int* __restrict__ esrc,
                                                const int* __restrict__ rowptr,
                                                const float* __restrict__ dinv,
                                                unsigned short* __restrict__ xab, int N) {
    int node = (blockIdx.x * blockDim.x + threadIdx.x) >> 5;
    int sub  = threadIdx.x & 31;
    if (node >= N) return;
    int eo = sub >> 4, cs = sub & 15;       // edge parity, col-chunk (8 bf16 = 16 B)
    int start = rowptr[node], end = rowptr[node + 1];
    float dd = dinv[node];
    float acc[8];
    #pragma unroll
    for (int j = 0; j < 8; ++j) acc[j] = 0.f;

    for (int base = start; base < end; base += 32) {
        int cnt = min(32, end - base);
        int myedge = 0; float mynorm = 0.f;
        if (sub < cnt) { myedge = esrc[base + sub]; mynorm = dinv[myedge]; }
        int pairs = (cnt + 1) >> 1;
        int i = 0;
        for (; i + 1 < pairs; i += 2) {
            int i0 = 2 * i + eo, i1 = 2 * i + 2 + eo;
            int   s0 = __shfl(myedge, i0, 32); float w0 = __shfl(mynorm, i0, 32);
            int   s1 = __shfl(myedge, i1, 32); float w1 = __shfl(mynorm, i1, 32);
            us8 v0 = *(const us8*)(xb + (size_t)s0 * D + cs * 8);
            us8 v1 = *(const us8*)(xb + (size_t)s1 * D + cs * 8);
            #pragma unroll
            for (int j = 0; j < 8; ++j) acc[j] += bf2f(v0[j]) * w0;
            #pragma unroll
            for (int j = 0; j < 8; ++j) acc[j] += bf2f(v1[j]) * w1;
        }
        for (; i < pairs; ++i) {
            int i0 = 2 * i + eo;
            int   s0 = __shfl(myedge, i0, 32); float w0 = __shfl(mynorm, i0, 32);
            us8 v0 = *(const us8*)(xb + (size_t)s0 * D + cs * 8);
            #pragma unroll
            for (int j = 0; j < 8; ++j) acc[j] += bf2f(v0[j]) * w0;
        }
    }
    // combine the two edge-parity halves
    #pragma unroll
    for (int j = 0; j < 8; ++j) acc[j] += __shfl_xor(acc[j], 16);
    if (eo == 0) {
        us8 xs = *(const us8*)(xb + (size_t)node * D + cs * 8);
        float sfac = 2.f * dd * dd;
        us8 r;
        #pragma unroll
        for (int j = 0; j < 8; ++j) r[j] = f2bf(acc[j] * dd + bf2f(xs[j]) * sfac);
        *(us8*)(xab + (size_t)node * D + cs * 8) = r;
    }
}

// ---------- fold weights into Mt[col][k] bf16 (col<128: Wz@lzW_top, col>=128: Wh@lhW_top) ----------
__global__ void k_prep(const float* __restrict__ Wz, const float* __restrict__ bz,
                       const float* __restrict__ lzW, const float* __restrict__ lzb,
                       const float* __restrict__ Wh, const float* __restrict__ bh,
                       const float* __restrict__ lhW, const float* __restrict__ lhb,
                       unsigned short* __restrict__ Mt, float* __restrict__ c) {
    int j = threadIdx.x;   // 0..255 (output col)
    int k = blockIdx.x;    // 0..127 (input k)
    int jj = j & 127;
    const float* W = (j < 128) ? Wz : Wh;
    const float* L = (j < 128) ? lzW : lhW;   // only first 128 rows used (H0 part is zero)
    float s = 0.f;
    for (int t = 0; t < 128; ++t) s += W[k * 128 + t] * L[t * 128 + jj];
    Mt[(size_t)j * 128 + k] = f2bf(s);
    if (k == 0) {
        const float* b  = (j < 128) ? bz  : bh;
        const float* lb = (j < 128) ? lzb : lhb;
        float cs = lb[jj];
        for (int t = 0; t < 128; ++t) cs += b[t] * L[t * 128 + jj];
        c[j] = cs;
    }
}

// ---------- MFMA epilogue: one wave per 16-node tile, all 256 cols, fused act+W2 ----------
__global__ __launch_bounds__(256, 2) void k_ep_mfma(
    const unsigned short* __restrict__ xab, const unsigned short* __restrict__ Mt,
    const float* __restrict__ c, const float* __restrict__ W2,
    const float* __restrict__ b2, float* __restrict__ out, int N) {
    int wave = (blockIdx.x * blockDim.x + threadIdx.x) >> 6;
    int lane = threadIdx.x & 63;
    int ntiles = (N + 15) >> 4;
    if (wave >= ntiles) return;
    int n0 = wave << 4;
    int l = lane & 15, q = lane >> 4;

    f4v acc[16];
    #pragma unroll
    for (int t = 0; t < 16; ++t) acc[t] = (f4v){0.f, 0.f, 0.f, 0.f};

    const unsigned short* abase = xab + (size_t)(n0 + l) * D + q * 8;
    const unsigned short* bbase = Mt + (size_t)l * 128 + q * 8;

    #pragma unroll
    for (int ks = 0; ks < 4; ++ks) {
        s8v a = *(const s8v*)(abase + ks * 32);
        #pragma unroll
        for (int t = 0; t < 16; ++t) {
            s8v b = *(const s8v*)(bbase + (size_t)t * 16 * 128 + ks * 32);
            acc[t] = __builtin_amdgcn_mfma_f32_16x16x32_bf16(a, b, acc[t], 0, 0, 0);
        }
    }

    // fused activation + W2 dot: z tiles t=0..7 (col=16t+l), h tiles t+8 (col 128+16t+l)
    float p[4] = {0.f, 0.f, 0.f, 0.f};
    #pragma unroll
    for (int t = 0; t < 8; ++t) {
        int col = t * 16 + l;
        #pragma unroll
        for (int r = 0; r < 4; ++r) {
            float gz = acc[t][r]     + c[col];
            float gh = acc[t + 8][r] + c[128 + col];
            float z  = 1.f / (1.f + __expf(-gz));
            float ht = tanhf(gh);
            p[r] += (1.f - z) * ht * W2[col];
        }
    }
    // reduce over cols (lane bits 0..3)
    #pragma unroll
    for (int r = 0; r < 4; ++r) {
        p[r] += __shfl_xor(p[r], 1);
        p[r] += __shfl_xor(p[r], 2);
        p[r] += __shfl_xor(p[r], 4);
        p[r] += __shfl_xor(p[r], 8);
    }
    if (l == 0) {
        float bb = b2[0];
        #pragma unroll
        for (int r = 0; r < 4; ++r) {
            int n = n0 + q * 4 + r;                // C/D row = quad*4 + reg
            if (n < N) out[n] = p[r] + bb;
        }
    }
}

extern "C" void kernel_launch(void* const* d_in, const int* in_sizes, int n_in,
                              void* d_out, int out_size, void* d_ws, size_t ws_size,
                              hipStream_t stream) {
    const float* x    = (const float*)d_in[0];
    const int*   eidx = (const int*)d_in[1];
    const float* Wz   = (const float*)d_in[2];
    const float* bz   = (const float*)d_in[3];
    const float* Wh   = (const float*)d_in[6];
    const float* bh   = (const float*)d_in[7];
    const float* lzW  = (const float*)d_in[8];
    const float* lzb  = (const float*)d_in[9];
    const float* lhW  = (const float*)d_in[12];
    const float* lhb  = (const float*)d_in[13];
    const float* W2   = (const float*)d_in[14];
    const float* b2   = (const float*)d_in[15];
    float* out = (float*)d_out;

    int N = in_sizes[0] / D;          // 100000
    int E = in_sizes[1] / 2;          // 1600000
    const int* src = eidx;
    const int* dst = eidx + E;
    int B = (N + SCAN_B - 1) / SCAN_B;

    // workspace layout (bytes), 512-aligned segments
    char* ws = (char*)d_ws;
    size_t off = 0;
    auto alloc = [&](size_t bytes) { void* p = ws + off; off += (bytes + 511) & ~(size_t)511; return p; };
    unsigned short* xb   = (unsigned short*)alloc((size_t)N * D * 2);
    unsigned short* xab  = (unsigned short*)alloc((size_t)N * D * 2);
    int*   counts = (int*)  alloc((size_t)N * 4);
    int*   rowptr = (int*)  alloc((size_t)(N + 1) * 4);
    float* dinv   = (float*)alloc((size_t)N * 4);
    int*   esrc   = (int*)  alloc((size_t)E * 4);
    int*   bsum   = (int*)  alloc((size_t)B * 4);
    unsigned short* Mt = (unsigned short*)alloc(256 * 128 * 2);
    float* c      = (float*)alloc(256 * 4);

    hipMemsetAsync(counts, 0, (size_t)N * sizeof(int), stream);

    k_count<<<(E + 255) / 256, 256, 0, stream>>>(dst, E, counts);
    k_bsum<<<B, 256, 0, stream>>>(counts, N, bsum);
    k_scan_bsum<<<1, 64, 0, stream>>>(bsum, B, rowptr, N);
    k_scan_fill<<<B, 256, 0, stream>>>(counts, N, bsum, rowptr);
    k_dinv<<<(N + 255) / 256, 256, 0, stream>>>(counts, dinv, N);
    k_place<<<(E + 255) / 256, 256, 0, stream>>>(src, dst, E, rowptr, counts, esrc);
    k_xcast<<<(N * (D / 4) + 255) / 256, 256, 0, stream>>>(x, xb, N * (D / 4));
    k_gather<<<(N * 32 + 255) / 256, 256, 0, stream>>>(xb, esrc, rowptr, dinv, xab, N);
    k_prep<<<128, 256, 0, stream>>>(Wz, bz, lzW, lzb, Wh, bh, lhW, lhb, Mt, c);
    int ntiles = (N + 15) / 16;
    k_ep_mfma<<<(ntiles * 64 + 255) / 256, 256, 0, stream>>>(xab, Mt, c, W2, b2, out, N);
}